// Round 11
// baseline (144.715 us; speedup 1.0000x reference)
//
#include <hip/hip_runtime.h>
#include <cstdint>
#include <cstddef>

// Problem constants (match reference)
#define BATCH 16
#define NBLK 16
#define TB 256
#define EMBED 2048
#define NKV 8
#define GQ 4          // group size = NH / NKV = 32/8
#define HD 64
#define NQROWS 3072   // 2048 (q) + 512 (k_cur) + 512 (v_cur)
#define QSCALE 0.18033688011112042f  // 64^-0.5 * log2(e); scores in log2 domain

// Workspace layout (floats):
#define OFF_PARTMS 49152
#define OFF_PARTO  65536
#define OFF_ATTEN  589824

typedef float f32x4 __attribute__((ext_vector_type(4)));

__device__ __forceinline__ float dot4(float4 a, float4 b) {
  return a.x * b.x + a.y * b.y + a.z * b.z + a.w * b.w;
}
__device__ __forceinline__ float dot4x(float4 a, f32x4 b) {
  return a.x * b.x + a.y * b.y + a.z * b.z + a.w * b.w;
}

// Nontemporal 16B load (one-touch streams: W matrices).
__device__ __forceinline__ float4 ntload4(const float* p) {
  f32x4 v = __builtin_nontemporal_load(reinterpret_cast<const f32x4*>(p));
  return make_float4(v.x, v.y, v.z, v.w);
}

// 8 nontemporal 16B loads in ONE asm block: 4 K tokens + 4 V tokens.
// j-th load at byte offset j*1024 (= 4 tokens * 256 B).
__device__ __forceinline__ void burst8(const float* kp, const float* vp,
                                       f32x4& k0, f32x4& k1, f32x4& k2, f32x4& k3,
                                       f32x4& v0, f32x4& v1, f32x4& v2, f32x4& v3) {
  asm volatile(
      "global_load_dwordx4 %0, %8, off nt\n\t"
      "global_load_dwordx4 %1, %8, off offset:1024 nt\n\t"
      "global_load_dwordx4 %2, %8, off offset:2048 nt\n\t"
      "global_load_dwordx4 %3, %8, off offset:3072 nt\n\t"
      "global_load_dwordx4 %4, %9, off nt\n\t"
      "global_load_dwordx4 %5, %9, off offset:1024 nt\n\t"
      "global_load_dwordx4 %6, %9, off offset:2048 nt\n\t"
      "global_load_dwordx4 %7, %9, off offset:3072 nt"
      : "=v"(k0), "=v"(k1), "=v"(k2), "=v"(k3),
        "=v"(v0), "=v"(v1), "=v"(v2), "=v"(v3)
      : "v"(kp), "v"(vp));
}

#define WAIT8 do { asm volatile("s_waitcnt vmcnt(8)" ::: "memory"); \
                   __builtin_amdgcn_sched_barrier(0); } while (0)
#define WAIT0 do { asm volatile("s_waitcnt vmcnt(0)" ::: "memory"); \
                   __builtin_amdgcn_sched_barrier(0); } while (0)

// DPP-based sum over each 16-lane group (pure VALU, no LDS pipe).
template <int CTRL>
__device__ __forceinline__ float dpp_add(float x) {
  return x + __int_as_float(
                 __builtin_amdgcn_mov_dpp(__float_as_int(x), CTRL, 0xF, 0xF, true));
}
__device__ __forceinline__ float red16(float x) {
  x = dpp_add<0xB1>(x);   // quad_perm xor 1
  x = dpp_add<0x4E>(x);   // quad_perm xor 2
  x = dpp_add<0x124>(x);  // row_ror:4
  x = dpp_add<0x128>(x);  // row_ror:8
  return x;
}

// ---------------------------------------------------------------------------
// Kernel 1: fused q/k/v projection.  proj[b][i] = dot(W_all[i], x[b])
// W rows are one-touch -> nt loads; x stays cached.
// ---------------------------------------------------------------------------
#define PROJ_RPB 4
__global__ __launch_bounds__(256) void proj_kernel(
    const float* __restrict__ x, const float* __restrict__ Wq,
    const float* __restrict__ Wk, const float* __restrict__ Wv,
    float* __restrict__ proj) {
  int tid = threadIdx.x;
  int bb = tid & 15, kc = tid >> 4;
  int row0 = blockIdx.x * PROJ_RPB;
  const float* xp = x + (size_t)bb * EMBED + kc * 128;
  const float* wr[PROJ_RPB];
#pragma unroll
  for (int r = 0; r < PROJ_RPB; ++r) {
    int row = row0 + r;
    wr[r] = (row < 2048 ? Wq + (size_t)row * EMBED
             : row < 2560 ? Wk + (size_t)(row - 2048) * EMBED
                          : Wv + (size_t)(row - 2560) * EMBED) + kc * 128;
  }
  float a[PROJ_RPB] = {0.f, 0.f, 0.f, 0.f};
#pragma unroll
  for (int k = 0; k < 128; k += 8) {
    float4 x0 = *reinterpret_cast<const float4*>(xp + k);
    float4 x1 = *reinterpret_cast<const float4*>(xp + k + 4);
#pragma unroll
    for (int r = 0; r < PROJ_RPB; ++r) {
      float4 w0 = ntload4(wr[r] + k);
      float4 w1 = ntload4(wr[r] + k + 4);
      a[r] += dot4(w0, x0) + dot4(w1, x1);
    }
  }
  int w = tid >> 6, lane = tid & 63;
  __shared__ float red[4][PROJ_RPB][16];
#pragma unroll
  for (int r = 0; r < PROJ_RPB; ++r) {
    float s = a[r];
    s += __shfl_xor(s, 16);
    s += __shfl_xor(s, 32);
    if (lane < 16) red[w][r][lane] = s;
  }
  __syncthreads();
  if (tid < 16 * PROJ_RPB) {
    int r = tid >> 4, b2 = tid & 15;
    float v = red[0][r][b2] + red[1][r][b2] + red[2][r][b2] + red[3][r][b2];
    proj[(size_t)b2 * NQROWS + row0 + r] = v;
  }
}

// ---------------------------------------------------------------------------
// Kernel 2: fused flash-decode, asm-burst double-buffered KV pipeline.
// One KV-cache block per workgroup; each wave owns 64 tokens.
// Masks computed inline from wave-uniform `valid` (no persistent bool regs).
// ---------------------------------------------------------------------------
__device__ __forceinline__ void batch16m(const float4 qv[GQ], const f32x4 kv[4],
                                         const f32x4 vv[4], int tokbase, int sub,
                                         int valid, float m[GQ], float sm[GQ],
                                         float4 acc[GQ]) {
  float s[4][GQ];
#pragma unroll
  for (int j = 0; j < 4; ++j)
#pragma unroll
    for (int gi = 0; gi < GQ; ++gi) s[j][gi] = dot4x(qv[gi], kv[j]);
#pragma unroll
  for (int j = 0; j < 4; ++j) {
    bool ok = (tokbase + j * 4 + sub) < valid;
#pragma unroll
    for (int gi = 0; gi < GQ; ++gi) {
      s[j][gi] = red16(s[j][gi]);
      if (!ok) s[j][gi] = -1e30f;
    }
  }
#pragma unroll
  for (int gi = 0; gi < GQ; ++gi) {
    float bm = fmaxf(fmaxf(s[0][gi], s[1][gi]), fmaxf(s[2][gi], s[3][gi]));
    float mn = fmaxf(m[gi], bm);
    float c = exp2f(m[gi] - mn);
    float p0 = exp2f(s[0][gi] - mn);
    float p1 = exp2f(s[1][gi] - mn);
    float p2 = exp2f(s[2][gi] - mn);
    float p3 = exp2f(s[3][gi] - mn);
    sm[gi] = sm[gi] * c + ((p0 + p1) + (p2 + p3));
    acc[gi].x = acc[gi].x * c + (p0 * vv[0].x + p1 * vv[1].x + p2 * vv[2].x + p3 * vv[3].x);
    acc[gi].y = acc[gi].y * c + (p0 * vv[0].y + p1 * vv[1].y + p2 * vv[2].y + p3 * vv[3].y);
    acc[gi].z = acc[gi].z * c + (p0 * vv[0].z + p1 * vv[1].z + p2 * vv[2].z + p3 * vv[3].z);
    acc[gi].w = acc[gi].w * c + (p0 * vv[0].w + p1 * vv[1].w + p2 * vv[2].w + p3 * vv[3].w);
    m[gi] = mn;
  }
}

__global__ __launch_bounds__(256) void attn_partial_kernel(
    const float* __restrict__ blocks_k, const float* __restrict__ blocks_v,
    const float* __restrict__ proj, const int* __restrict__ last_offset,
    float* __restrict__ part_ms, float* __restrict__ part_o) {
  int nb = blockIdx.x, b = blockIdx.y, h = blockIdx.z;
  int tid = threadIdx.x;
  int w = tid >> 6, lane = tid & 63;
  int sub = lane >> 4, dl = (lane & 15) * 4;

  int valid = (nb == NBLK - 1) ? last_offset[0] : TB;

  // q fragments, pre-scaled by 1/sqrt(d) * log2(e) (log2-domain softmax)
  float4 qv[GQ];
  const float* qbase = proj + (size_t)b * NQROWS + h * GQ * HD + dl;
#pragma unroll
  for (int gi = 0; gi < GQ; ++gi) {
    float4 q = *reinterpret_cast<const float4*>(qbase + gi * HD);
    qv[gi] = make_float4(q.x * QSCALE, q.y * QSCALE, q.z * QSCALE, q.w * QSCALE);
  }

  size_t kvoff = (((size_t)nb * BATCH + b) * NKV + h) * (size_t)(TB * HD);
  const float* kp = blocks_k + kvoff + (size_t)(w * 64 + sub) * HD + dl;
  const float* vp = blocks_v + kvoff + (size_t)(w * 64 + sub) * HD + dl;

  float m[GQ], sm[GQ];
  float4 acc[GQ];
#pragma unroll
  for (int gi = 0; gi < GQ; ++gi) {
    m[gi] = -1e30f;
    sm[gi] = 0.f;
    acc[gi] = make_float4(0.f, 0.f, 0.f, 0.f);
  }

  // Drain compiler-issued loads (q, valid) so vmcnt counting is exact.
  asm volatile("s_waitcnt vmcnt(0)" ::: "memory");

  f32x4 ka[4], va[4], kb[4], vb[4];
  int tb0 = w * 64;
  // prologue: tile 0 -> A
  burst8(kp, vp, ka[0], ka[1], ka[2], ka[3], va[0], va[1], va[2], va[3]);
  // tile 1 -> B; wait A; compute A
  burst8(kp + 16 * HD, vp + 16 * HD, kb[0], kb[1], kb[2], kb[3],
         vb[0], vb[1], vb[2], vb[3]);
  WAIT8;
  batch16m(qv, ka, va, tb0 + 0, sub, valid, m, sm, acc);
  // tile 2 -> A; wait B; compute B
  burst8(kp + 32 * HD, vp + 32 * HD, ka[0], ka[1], ka[2], ka[3],
         va[0], va[1], va[2], va[3]);
  WAIT8;
  batch16m(qv, kb, vb, tb0 + 16, sub, valid, m, sm, acc);
  // tile 3 -> B; wait A; compute A
  burst8(kp + 48 * HD, vp + 48 * HD, kb[0], kb[1], kb[2], kb[3],
         vb[0], vb[1], vb[2], vb[3]);
  WAIT8;
  batch16m(qv, ka, va, tb0 + 32, sub, valid, m, sm, acc);
  // wait B; compute B
  WAIT0;
  batch16m(qv, kb, vb, tb0 + 48, sub, valid, m, sm, acc);

  // merge the 4 token sub-slots (lane bits 4,5)
#pragma unroll
  for (int mask = 16; mask <= 32; mask <<= 1) {
#pragma unroll
    for (int gi = 0; gi < GQ; ++gi) {
      float mo = __shfl_xor(m[gi], mask);
      float so = __shfl_xor(sm[gi], mask);
      float4 ao;
      ao.x = __shfl_xor(acc[gi].x, mask);
      ao.y = __shfl_xor(acc[gi].y, mask);
      ao.z = __shfl_xor(acc[gi].z, mask);
      ao.w = __shfl_xor(acc[gi].w, mask);
      float mn = fmaxf(m[gi], mo);
      float c1 = exp2f(m[gi] - mn);
      float c2 = exp2f(mo - mn);
      sm[gi] = sm[gi] * c1 + so * c2;
      acc[gi].x = acc[gi].x * c1 + ao.x * c2;
      acc[gi].y = acc[gi].y * c1 + ao.y * c2;
      acc[gi].z = acc[gi].z * c1 + ao.z * c2;
      acc[gi].w = acc[gi].w * c1 + ao.w * c2;
      m[gi] = mn;
    }
  }

  // cross-wave merge via LDS; tail distributed: wave w handles gi = w.
  __shared__ float lds_o[4][GQ][HD];
  __shared__ float lds_m[4][GQ];
  __shared__ float lds_s[4][GQ];
  if (lane < 16) {
#pragma unroll
    for (int gi = 0; gi < GQ; ++gi)
      *reinterpret_cast<float4*>(&lds_o[w][gi][dl]) = acc[gi];
    if (lane == 0) {
#pragma unroll
      for (int gi = 0; gi < GQ; ++gi) {
        lds_m[w][gi] = m[gi];
        lds_s[w][gi] = sm[gi];
      }
    }
  }
  __syncthreads();

  {
    int gi = w;      // each wave finalizes one query head
    int d = lane;    // 0..63
    float M = fmaxf(fmaxf(lds_m[0][gi], lds_m[1][gi]),
                    fmaxf(lds_m[2][gi], lds_m[3][gi]));
    float sum = 0.f, o = 0.f;
#pragma unroll
    for (int ww = 0; ww < 4; ++ww) {
      float c = exp2f(lds_m[ww][gi] - M);
      sum += lds_s[ww][gi] * c;
      o += lds_o[ww][gi][d] * c;
    }
    size_t idx = (((size_t)b * NKV + h) * GQ + gi) * NBLK + nb;
    if (lane == 0) {
      part_ms[idx * 2] = M;
      part_ms[idx * 2 + 1] = sum;
    }
    part_o[idx * HD + d] = o;
  }
}

// ---------------------------------------------------------------------------
// Kernel 3: merge 16 block-partials + current token per (b,h,gi) (log2 domain).
// ---------------------------------------------------------------------------
__global__ __launch_bounds__(256) void reduce_kernel(
    const float* __restrict__ proj, const float* __restrict__ part_ms,
    const float* __restrict__ part_o, float* __restrict__ atten) {
  int tid = threadIdx.x;
  int wi = blockIdx.x * 4 + (tid >> 6);
  int lane = tid & 63;  // head-dim d
  int b = wi >> 5;
  int h = (wi >> 2) & 7;
  int gi = wi & 3;
  size_t pidx = (((size_t)b * NKV + h) * GQ + gi) * NBLK;

  float qd = proj[(size_t)b * NQROWS + (h * GQ + gi) * HD + lane];
  float kd = proj[(size_t)b * NQROWS + 2048 + h * HD + lane];
  float vd = proj[(size_t)b * NQROWS + 2560 + h * HD + lane];
  float sp = qd * kd;
#pragma unroll
  for (int mask = 1; mask < 64; mask <<= 1) sp += __shfl_xor(sp, mask);
  float s_cur = sp * QSCALE;  // log2 domain

  float pm[NBLK], ps[NBLK];
  float M = s_cur;
#pragma unroll
  for (int nb = 0; nb < NBLK; ++nb) {
    pm[nb] = part_ms[(pidx + nb) * 2];
    ps[nb] = part_ms[(pidx + nb) * 2 + 1];
    M = fmaxf(M, pm[nb]);
  }
  float p_cur = exp2f(s_cur - M);
  float sum = p_cur;
  float o = p_cur * vd;
#pragma unroll
  for (int nb = 0; nb < NBLK; ++nb) {
    float c = exp2f(pm[nb] - M);
    sum += ps[nb] * c;
    o += part_o[(pidx + nb) * HD + lane] * c;
  }
  atten[(size_t)b * EMBED + (h * GQ + gi) * HD + lane] = o / sum;
}

// ---------------------------------------------------------------------------
// Kernel 4: out[b][i] = dot(Wo[i], atten[b]) — Wo is one-touch -> nt loads.
// ---------------------------------------------------------------------------
#define OUT_RPB 4
__global__ __launch_bounds__(256) void out_kernel(
    const float* __restrict__ atten, const float* __restrict__ Wo,
    float* __restrict__ out) {
  int tid = threadIdx.x;
  int bb = tid & 15, kc = tid >> 4;
  int row0 = blockIdx.x * OUT_RPB;
  const float* xp = atten + (size_t)bb * EMBED + kc * 128;
  float a[OUT_RPB] = {0.f, 0.f, 0.f, 0.f};
#pragma unroll
  for (int k = 0; k < 128; k += 8) {
    float4 x0 = *reinterpret_cast<const float4*>(xp + k);
    float4 x1 = *reinterpret_cast<const float4*>(xp + k + 4);
#pragma unroll
    for (int r = 0; r < OUT_RPB; ++r) {
      const float* wp = Wo + (size_t)(row0 + r) * EMBED + kc * 128;
      float4 w0 = ntload4(wp + k);
      float4 w1 = ntload4(wp + k + 4);
      a[r] += dot4(w0, x0) + dot4(w1, x1);
    }
  }
  int w = tid >> 6, lane = tid & 63;
  __shared__ float red[4][OUT_RPB][16];
#pragma unroll
  for (int r = 0; r < OUT_RPB; ++r) {
    float s = a[r];
    s += __shfl_xor(s, 16);
    s += __shfl_xor(s, 32);
    if (lane < 16) red[w][r][lane] = s;
  }
  __syncthreads();
  if (tid < 16 * OUT_RPB) {
    int r = tid >> 4, b2 = tid & 15;
    float v = red[0][r][b2] + red[1][r][b2] + red[2][r][b2] + red[3][r][b2];
    out[(size_t)b2 * EMBED + row0 + r] = v;
  }
}

// ---------------------------------------------------------------------------
extern "C" void kernel_launch(void* const* d_in, const int* in_sizes, int n_in,
                              void* d_out, int out_size, void* d_ws, size_t ws_size,
                              hipStream_t stream) {
  const float* x = (const float*)d_in[0];
  const float* bk = (const float*)d_in[1];
  const float* bv = (const float*)d_in[2];
  const float* Wq = (const float*)d_in[3];
  const float* Wk = (const float*)d_in[4];
  const float* Wv = (const float*)d_in[5];
  const float* Wo = (const float*)d_in[6];
  const int* lo = (const int*)d_in[7];

  float* ws = (float*)d_ws;
  float* proj = ws;
  float* part_ms = ws + OFF_PARTMS;
  float* part_o = ws + OFF_PARTO;
  float* atten = ws + OFF_ATTEN;
  float* out = (float*)d_out;

  proj_kernel<<<NQROWS / PROJ_RPB, 256, 0, stream>>>(x, Wq, Wk, Wv, proj);
  attn_partial_kernel<<<dim3(NBLK, BATCH, NKV), 256, 0, stream>>>(
      bk, bv, proj, lo, part_ms, part_o);
  reduce_kernel<<<(BATCH * NKV * GQ) / 4, 256, 0, stream>>>(
      proj, part_ms, part_o, atten);
  out_kernel<<<EMBED / OUT_RPB, 256, 0, stream>>>(atten, Wo, out);
}

// Round 12
// 115.108 us; speedup vs baseline: 1.2572x; 1.2572x over previous
//
#include <hip/hip_runtime.h>
#include <cstdint>
#include <cstddef>

// Problem constants (match reference)
#define BATCH 16
#define NBLK 16
#define TB 256
#define EMBED 2048
#define NKV 8
#define GQ 4          // group size = NH / NKV = 32/8
#define HD 64
#define NQROWS 3072   // 2048 (q) + 512 (k_cur) + 512 (v_cur)
#define QSCALE 0.18033688011112042f  // 64^-0.5 * log2(e); scores in log2 domain

// Workspace layout (floats):
#define OFF_PROJHI 49152      // proj_lo at 0, proj_hi here (49152 each)
#define OFF_PARTMS 98304      // [B*NKV*GQ][NBLK][2]   (16384)
#define OFF_PARTO  114688     // [B*NKV*GQ][NBLK][HD]  (524288)
#define OFF_ATTEN  638976     // [B][EMBED]            (32768)

typedef float f32x4 __attribute__((ext_vector_type(4)));

__device__ __forceinline__ float dot4(float4 a, float4 b) {
  return a.x * b.x + a.y * b.y + a.z * b.z + a.w * b.w;
}

// Nontemporal 16B load (one-touch KV stream; no L3 allocation).
__device__ __forceinline__ float4 ntload4(const float* p) {
  f32x4 v = __builtin_nontemporal_load(reinterpret_cast<const f32x4*>(p));
  return make_float4(v.x, v.y, v.z, v.w);
}

// DPP-based sum over each 16-lane group (pure VALU, no LDS pipe).
template <int CTRL>
__device__ __forceinline__ float dpp_add(float x) {
  return x + __int_as_float(
                 __builtin_amdgcn_mov_dpp(__float_as_int(x), CTRL, 0xF, 0xF, true));
}
__device__ __forceinline__ float red16(float x) {
  x = dpp_add<0xB1>(x);   // quad_perm xor 1
  x = dpp_add<0x4E>(x);   // quad_perm xor 2
  x = dpp_add<0x124>(x);  // row_ror:4
  x = dpp_add<0x128>(x);  // row_ror:8
  return x;
}

// ---------------------------------------------------------------------------
// Kernel 1: fused q/k/v projection, split-K x2.
// Grid (NQROWS/4, 2): blockIdx.y = k-half. Each block: 4 rows x 16 batches,
// 16 k-chunks of 64 elems within its half. Partials -> proj_lo / proj_hi.
// ---------------------------------------------------------------------------
#define PROJ_RPB 4
__global__ __launch_bounds__(256) void proj_kernel(
    const float* __restrict__ x, const float* __restrict__ Wq,
    const float* __restrict__ Wk, const float* __restrict__ Wv,
    float* __restrict__ proj_lo, float* __restrict__ proj_hi) {
  int tid = threadIdx.x;
  int bb = tid & 15, kc = tid >> 4;
  int half = blockIdx.y;
  int kbase = half * 1024 + kc * 64;
  int row0 = blockIdx.x * PROJ_RPB;
  float* proj = half ? proj_hi : proj_lo;
  const float* xp = x + (size_t)bb * EMBED + kbase;
  const float* wr[PROJ_RPB];
#pragma unroll
  for (int r = 0; r < PROJ_RPB; ++r) {
    int row = row0 + r;
    wr[r] = (row < 2048 ? Wq + (size_t)row * EMBED
             : row < 2560 ? Wk + (size_t)(row - 2048) * EMBED
                          : Wv + (size_t)(row - 2560) * EMBED) + kbase;
  }
  float a[PROJ_RPB] = {0.f, 0.f, 0.f, 0.f};
#pragma unroll
  for (int k = 0; k < 64; k += 8) {
    float4 x0 = *reinterpret_cast<const float4*>(xp + k);
    float4 x1 = *reinterpret_cast<const float4*>(xp + k + 4);
#pragma unroll
    for (int r = 0; r < PROJ_RPB; ++r) {
      float4 w0 = *reinterpret_cast<const float4*>(wr[r] + k);
      float4 w1 = *reinterpret_cast<const float4*>(wr[r] + k + 4);
      a[r] += dot4(w0, x0) + dot4(w1, x1);
    }
  }
  int w = tid >> 6, lane = tid & 63;
  __shared__ float red[4][PROJ_RPB][16];
#pragma unroll
  for (int r = 0; r < PROJ_RPB; ++r) {
    float s = a[r];
    s += __shfl_xor(s, 16);
    s += __shfl_xor(s, 32);
    if (lane < 16) red[w][r][lane] = s;
  }
  __syncthreads();
  if (tid < 16 * PROJ_RPB) {
    int r = tid >> 4, b2 = tid & 15;
    float v = red[0][r][b2] + red[1][r][b2] + red[2][r][b2] + red[3][r][b2];
    proj[(size_t)b2 * NQROWS + row0 + r] = v;
  }
}

// ---------------------------------------------------------------------------
// Kernel 2: fused flash-decode partials (r9 structure: compiler-scheduled
// nt loads — best measured). One KV-cache block per workgroup.
// ---------------------------------------------------------------------------
template <bool MASKED>
__device__ __forceinline__ void batch16(const float4 qv[GQ], const float4 kv[4],
                                        const float4 vv[4], const bool pr[4],
                                        float m[GQ], float sm[GQ], float4 acc[GQ]) {
  float s[4][GQ];
#pragma unroll
  for (int j = 0; j < 4; ++j)
#pragma unroll
    for (int gi = 0; gi < GQ; ++gi) s[j][gi] = dot4(qv[gi], kv[j]);
#pragma unroll
  for (int j = 0; j < 4; ++j)
#pragma unroll
    for (int gi = 0; gi < GQ; ++gi) {
      s[j][gi] = red16(s[j][gi]);
      if (MASKED && !pr[j]) s[j][gi] = -1e30f;
    }
#pragma unroll
  for (int gi = 0; gi < GQ; ++gi) {
    float bm = fmaxf(fmaxf(s[0][gi], s[1][gi]), fmaxf(s[2][gi], s[3][gi]));
    float mn = fmaxf(m[gi], bm);
    float c = exp2f(m[gi] - mn);
    float p0 = exp2f(s[0][gi] - mn);
    float p1 = exp2f(s[1][gi] - mn);
    float p2 = exp2f(s[2][gi] - mn);
    float p3 = exp2f(s[3][gi] - mn);
    sm[gi] = sm[gi] * c + ((p0 + p1) + (p2 + p3));
    acc[gi].x = acc[gi].x * c + (p0 * vv[0].x + p1 * vv[1].x + p2 * vv[2].x + p3 * vv[3].x);
    acc[gi].y = acc[gi].y * c + (p0 * vv[0].y + p1 * vv[1].y + p2 * vv[2].y + p3 * vv[3].y);
    acc[gi].z = acc[gi].z * c + (p0 * vv[0].z + p1 * vv[1].z + p2 * vv[2].z + p3 * vv[3].z);
    acc[gi].w = acc[gi].w * c + (p0 * vv[0].w + p1 * vv[1].w + p2 * vv[2].w + p3 * vv[3].w);
    m[gi] = mn;
  }
}

__global__ __launch_bounds__(256) void attn_partial_kernel(
    const float* __restrict__ blocks_k, const float* __restrict__ blocks_v,
    const float* __restrict__ proj_lo, const float* __restrict__ proj_hi,
    const int* __restrict__ last_offset,
    float* __restrict__ part_ms, float* __restrict__ part_o) {
  int nb = blockIdx.x, b = blockIdx.y, h = blockIdx.z;
  int tid = threadIdx.x;
  int w = tid >> 6, lane = tid & 63;
  int sub = lane >> 4, dl = (lane & 15) * 4;

  // q fragments = lo + hi, pre-scaled by 1/sqrt(d)*log2(e)
  float4 qv[GQ];
  size_t qoff = (size_t)b * NQROWS + h * GQ * HD + dl;
#pragma unroll
  for (int gi = 0; gi < GQ; ++gi) {
    float4 ql = *reinterpret_cast<const float4*>(proj_lo + qoff + gi * HD);
    float4 qh = *reinterpret_cast<const float4*>(proj_hi + qoff + gi * HD);
    qv[gi] = make_float4((ql.x + qh.x) * QSCALE, (ql.y + qh.y) * QSCALE,
                         (ql.z + qh.z) * QSCALE, (ql.w + qh.w) * QSCALE);
  }

  size_t kvoff = (((size_t)nb * BATCH + b) * NKV + h) * (size_t)(TB * HD);
  const float* kp = blocks_k + kvoff + (size_t)(w * 64 + sub) * HD + dl;
  const float* vp = blocks_v + kvoff + (size_t)(w * 64 + sub) * HD + dl;

  float m[GQ], sm[GQ];
  float4 acc[GQ];
#pragma unroll
  for (int gi = 0; gi < GQ; ++gi) {
    m[gi] = -1e30f;
    sm[gi] = 0.f;
    acc[gi] = make_float4(0.f, 0.f, 0.f, 0.f);
  }

  if (nb != NBLK - 1) {
    bool pr[4] = {true, true, true, true};
#pragma unroll
    for (int ot = 0; ot < 4; ++ot) {
      float4 kv[4], vv[4];
#pragma unroll
      for (int j = 0; j < 4; ++j)
        kv[j] = ntload4(kp + (ot * 16 + j * 4) * HD);
#pragma unroll
      for (int j = 0; j < 4; ++j)
        vv[j] = ntload4(vp + (ot * 16 + j * 4) * HD);
      batch16<false>(qv, kv, vv, pr, m, sm, acc);
    }
  } else {
    int valid = last_offset[0];
#pragma unroll
    for (int ot = 0; ot < 4; ++ot) {
      float4 kv[4], vv[4];
      bool pr[4];
#pragma unroll
      for (int j = 0; j < 4; ++j) {
        int tok = w * 64 + ot * 16 + j * 4 + sub;
        pr[j] = tok < valid;
        kv[j] = make_float4(0.f, 0.f, 0.f, 0.f);
        vv[j] = make_float4(0.f, 0.f, 0.f, 0.f);
        if (pr[j]) {
          kv[j] = ntload4(kp + (ot * 16 + j * 4) * HD);
          vv[j] = ntload4(vp + (ot * 16 + j * 4) * HD);
        }
      }
      batch16<true>(qv, kv, vv, pr, m, sm, acc);
    }
  }

  // merge the 4 token sub-slots (lane bits 4,5)
#pragma unroll
  for (int mask = 16; mask <= 32; mask <<= 1) {
#pragma unroll
    for (int gi = 0; gi < GQ; ++gi) {
      float mo = __shfl_xor(m[gi], mask);
      float so = __shfl_xor(sm[gi], mask);
      float4 ao;
      ao.x = __shfl_xor(acc[gi].x, mask);
      ao.y = __shfl_xor(acc[gi].y, mask);
      ao.z = __shfl_xor(acc[gi].z, mask);
      ao.w = __shfl_xor(acc[gi].w, mask);
      float mn = fmaxf(m[gi], mo);
      float c1 = exp2f(m[gi] - mn);
      float c2 = exp2f(mo - mn);
      sm[gi] = sm[gi] * c1 + so * c2;
      acc[gi].x = acc[gi].x * c1 + ao.x * c2;
      acc[gi].y = acc[gi].y * c1 + ao.y * c2;
      acc[gi].z = acc[gi].z * c1 + ao.z * c2;
      acc[gi].w = acc[gi].w * c1 + ao.w * c2;
      m[gi] = mn;
    }
  }

  // cross-wave merge via LDS
  __shared__ float lds_o[4][GQ][HD];
  __shared__ float lds_m[4][GQ];
  __shared__ float lds_s[4][GQ];
  if (lane < 16) {
#pragma unroll
    for (int gi = 0; gi < GQ; ++gi)
      *reinterpret_cast<float4*>(&lds_o[w][gi][dl]) = acc[gi];
    if (lane == 0) {
#pragma unroll
      for (int gi = 0; gi < GQ; ++gi) {
        lds_m[w][gi] = m[gi];
        lds_s[w][gi] = sm[gi];
      }
    }
  }
  __syncthreads();

  if (w == 0) {
    int d = lane;  // 0..63
#pragma unroll
    for (int gi = 0; gi < GQ; ++gi) {
      float M = fmaxf(fmaxf(lds_m[0][gi], lds_m[1][gi]),
                      fmaxf(lds_m[2][gi], lds_m[3][gi]));
      float sum = 0.f, o = 0.f;
#pragma unroll
      for (int ww = 0; ww < 4; ++ww) {
        float c = exp2f(lds_m[ww][gi] - M);
        sum += lds_s[ww][gi] * c;
        o += lds_o[ww][gi][d] * c;
      }
      size_t idx = (((size_t)b * NKV + h) * GQ + gi) * NBLK + nb;
      if (lane == 0) {
        part_ms[idx * 2] = M;
        part_ms[idx * 2 + 1] = sum;
      }
      part_o[idx * HD + d] = o;
    }
  }
}

// ---------------------------------------------------------------------------
// Kernel 3: merge 16 block-partials + current token per (b,h,gi) (log2 domain).
// ---------------------------------------------------------------------------
__global__ __launch_bounds__(256) void reduce_kernel(
    const float* __restrict__ proj_lo, const float* __restrict__ proj_hi,
    const float* __restrict__ part_ms, const float* __restrict__ part_o,
    float* __restrict__ atten) {
  int tid = threadIdx.x;
  int wi = blockIdx.x * 4 + (tid >> 6);
  int lane = tid & 63;  // head-dim d
  int b = wi >> 5;
  int h = (wi >> 2) & 7;
  int gi = wi & 3;
  size_t pidx = (((size_t)b * NKV + h) * GQ + gi) * NBLK;

  size_t base = (size_t)b * NQROWS;
  float qd = proj_lo[base + (h * GQ + gi) * HD + lane] +
             proj_hi[base + (h * GQ + gi) * HD + lane];
  float kd = proj_lo[base + 2048 + h * HD + lane] +
             proj_hi[base + 2048 + h * HD + lane];
  float vd = proj_lo[base + 2560 + h * HD + lane] +
             proj_hi[base + 2560 + h * HD + lane];
  float sp = qd * kd;
#pragma unroll
  for (int mask = 1; mask < 64; mask <<= 1) sp += __shfl_xor(sp, mask);
  float s_cur = sp * QSCALE;  // log2 domain

  float pm[NBLK], ps[NBLK];
  float M = s_cur;
#pragma unroll
  for (int nb = 0; nb < NBLK; ++nb) {
    pm[nb] = part_ms[(pidx + nb) * 2];
    ps[nb] = part_ms[(pidx + nb) * 2 + 1];
    M = fmaxf(M, pm[nb]);
  }
  float p_cur = exp2f(s_cur - M);
  float sum = p_cur;
  float o = p_cur * vd;
#pragma unroll
  for (int nb = 0; nb < NBLK; ++nb) {
    float c = exp2f(pm[nb] - M);
    sum += ps[nb] * c;
    o += part_o[(pidx + nb) * HD + lane] * c;
  }
  atten[(size_t)b * EMBED + (h * GQ + gi) * HD + lane] = o / sum;
}

// ---------------------------------------------------------------------------
// Kernel 4: out[b][i] = dot(Wo[i], atten[b])
// ---------------------------------------------------------------------------
#define OUT_RPB 4
__global__ __launch_bounds__(256) void out_kernel(
    const float* __restrict__ atten, const float* __restrict__ Wo,
    float* __restrict__ out) {
  int tid = threadIdx.x;
  int bb = tid & 15, kc = tid >> 4;
  int row0 = blockIdx.x * OUT_RPB;
  const float* xp = atten + (size_t)bb * EMBED + kc * 128;
  float a[OUT_RPB] = {0.f, 0.f, 0.f, 0.f};
#pragma unroll
  for (int k = 0; k < 128; k += 8) {
    float4 x0 = *reinterpret_cast<const float4*>(xp + k);
    float4 x1 = *reinterpret_cast<const float4*>(xp + k + 4);
#pragma unroll
    for (int r = 0; r < OUT_RPB; ++r) {
      const float* wp = Wo + (size_t)(row0 + r) * EMBED + kc * 128;
      float4 w0 = *reinterpret_cast<const float4*>(wp + k);
      float4 w1 = *reinterpret_cast<const float4*>(wp + k + 4);
      a[r] += dot4(w0, x0) + dot4(w1, x1);
    }
  }
  int w = tid >> 6, lane = tid & 63;
  __shared__ float red[4][OUT_RPB][16];
#pragma unroll
  for (int r = 0; r < OUT_RPB; ++r) {
    float s = a[r];
    s += __shfl_xor(s, 16);
    s += __shfl_xor(s, 32);
    if (lane < 16) red[w][r][lane] = s;
  }
  __syncthreads();
  if (tid < 16 * OUT_RPB) {
    int r = tid >> 4, b2 = tid & 15;
    float v = red[0][r][b2] + red[1][r][b2] + red[2][r][b2] + red[3][r][b2];
    out[(size_t)b2 * EMBED + row0 + r] = v;
  }
}

// ---------------------------------------------------------------------------
extern "C" void kernel_launch(void* const* d_in, const int* in_sizes, int n_in,
                              void* d_out, int out_size, void* d_ws, size_t ws_size,
                              hipStream_t stream) {
  const float* x = (const float*)d_in[0];
  const float* bk = (const float*)d_in[1];
  const float* bv = (const float*)d_in[2];
  const float* Wq = (const float*)d_in[3];
  const float* Wk = (const float*)d_in[4];
  const float* Wv = (const float*)d_in[5];
  const float* Wo = (const float*)d_in[6];
  const int* lo = (const int*)d_in[7];

  float* ws = (float*)d_ws;
  float* proj_lo = ws;
  float* proj_hi = ws + OFF_PROJHI;
  float* part_ms = ws + OFF_PARTMS;
  float* part_o = ws + OFF_PARTO;
  float* atten = ws + OFF_ATTEN;
  float* out = (float*)d_out;

  proj_kernel<<<dim3(NQROWS / PROJ_RPB, 2), 256, 0, stream>>>(x, Wq, Wk, Wv,
                                                              proj_lo, proj_hi);
  attn_partial_kernel<<<dim3(NBLK, BATCH, NKV), 256, 0, stream>>>(
      bk, bv, proj_lo, proj_hi, lo, part_ms, part_o);
  reduce_kernel<<<(BATCH * NKV * GQ) / 4, 256, 0, stream>>>(
      proj_lo, proj_hi, part_ms, part_o, atten);
  out_kernel<<<EMBED / OUT_RPB, 256, 0, stream>>>(atten, Wo, out);
}